// Round 3
// baseline (260.494 us; speedup 1.0000x reference)
//
#include <hip/hip_runtime.h>

// ROI bilinear pooling (tf.image.resize half-pixel centers), POOL=7.
// img: (1, 64, 64, 1024) fp32, NHWC. rois: (1, R, 4) int32 = [x, y, w, h].
// out: (1, R, 7, 7, 1024) fp32.
//
// R7 = fine-grained source-row ordering. Theory: the 205 MB write stream
// cycles each XCD's 4 MB L2 every ~5us, so the ~822 MB of tap reads all
// miss to L3 (explains pool ~108us and insensitivity to R3/R5/R6 edits).
// Coarse ROI-sort (R5) left a 5.9 MB/XCD window -> still thrashed.
// Change: sort the 7168 (roi,py) ROWS by their actual source row y0.
// A y0-ordered sweep reads a rolling window of ~2-3 image rows
// (~0.5-0.75 MB/XCD) -- small enough to survive write-thrash in L2.
// Pool body = R6 (streaming px loop, 4 blocks/CU, plain stores).

#define POOLSZ 7
#define IMG_H 64
#define IMG_W 64
#define IMG_C 1024
#define NUM_XCD 8

typedef float v4f __attribute__((ext_vector_type(4)));

__device__ __forceinline__ int src_y0(int ry, int rh, int py) {
    const float scy  = (float)rh * (1.0f / (float)POOLSZ);
    const float srcy = ((float)py + 0.5f) * scy - 0.5f;
    const int   iy   = (int)floorf(srcy);
    return ry + min(max(iy, 0), rh - 1);
}

// Counting-sort the R*7 (roi,py) rows by source row y0 (64 bins).
// One block, 256 threads, ~3 us. order[] = permutation of 0..R*7-1.
__global__ __launch_bounds__(256) void row_sort_kernel(
    const int* __restrict__ rois, int* __restrict__ order, int R) {
    __shared__ int cnt[64];
    __shared__ int ofs[64];
    const int t = threadIdx.x;
    const int n = R * POOLSZ;
    if (t < 64) cnt[t] = 0;
    __syncthreads();
    for (int i = t; i < n; i += 256) {
        const int r  = i / POOLSZ;
        const int py = i - r * POOLSZ;
        const int y0 = src_y0(rois[r * 4 + 1], rois[r * 4 + 3], py) & 63;
        atomicAdd(&cnt[y0], 1);
    }
    __syncthreads();
    if (t == 0) {
        int s = 0;
        for (int i = 0; i < 64; ++i) { ofs[i] = s; s += cnt[i]; }
    }
    __syncthreads();
    for (int i = t; i < n; i += 256) {
        const int r  = i / POOLSZ;
        const int py = i - r * POOLSZ;
        const int y0 = src_y0(rois[r * 4 + 1], rois[r * 4 + 3], py) & 63;
        const int p  = atomicAdd(&ofs[y0], 1);
        order[p] = i;   // permutation by construction
    }
}

// One block per (roi, py) row: 7 output cells. 256 threads, each owns a
// float4 channel slice. Streaming per-px: 4 taps -> blend -> store.
__global__ __launch_bounds__(256, 4) void roi_pool_row_kernel(
    const float* __restrict__ img,
    const int* __restrict__ rois,
    float* __restrict__ out,
    int rowsPerXcd,              // R*7/8 when divisible, else 0 (identity)
    const int* __restrict__ order) {  // y0-sorted row permutation, or null
    int rowIdx;
    if (rowsPerXcd > 0) {
        // xcd = blockIdx % 8; contiguous sorted chunk per XCD.
        const int xcd   = blockIdx.x & (NUM_XCD - 1);
        const int local = blockIdx.x >> 3;
        rowIdx = xcd * rowsPerXcd + local;
    } else {
        rowIdx = blockIdx.x;
    }
    const int rid = order ? order[rowIdx] : rowIdx;  // source-row ordering
    const int r  = rid / POOLSZ;
    const int py = rid - r * POOLSZ;

    const int4 roi = ((const int4*)rois)[r];
    const int rx = roi.x, ry = roi.y, rw = roi.z, rh = roi.w;

    // y coords: src = (py+0.5)*h/7 - 0.5; lerp from unclipped floor (ref semantics)
    const float scy  = (float)rh * (1.0f / (float)POOLSZ);
    const float srcy = ((float)py + 0.5f) * scy - 0.5f;
    const float fy   = floorf(srcy);
    const float ty   = srcy - fy;
    const int   iy   = (int)fy;
    const int   y0   = ry + min(max(iy,     0), rh - 1);
    const int   y1   = ry + min(max(iy + 1, 0), rh - 1);

    const int c4 = threadIdx.x;                       // 0..255: float4 channel slice
    const v4f* __restrict__ base = (const v4f*)img + c4;
    const int rb0 = y0 * (IMG_W * IMG_C / 4);         // 32-bit v4f-element offsets
    const int rb1 = y1 * (IMG_W * IMG_C / 4);

    v4f* __restrict__ dst =
        (v4f*)out + ((size_t)r * POOLSZ + py) * POOLSZ * (IMG_C / 4) + c4;

    const float scx = (float)rw * (1.0f / (float)POOLSZ);
#pragma unroll
    for (int px = 0; px < POOLSZ; ++px) {
        const float srcx = ((float)px + 0.5f) * scx - 0.5f;
        const float fx   = floorf(srcx);
        const float tx   = srcx - fx;
        const int   ix   = (int)fx;
        const int   xo0  = (rx + min(max(ix,     0), rw - 1)) * (IMG_C / 4);
        const int   xo1  = (rx + min(max(ix + 1, 0), rw - 1)) * (IMG_C / 4);

        const v4f a = base[rb0 + xo0];
        const v4f b = base[rb0 + xo1];
        const v4f c = base[rb1 + xo0];
        const v4f d = base[rb1 + xo1];

        const v4f top = a + (b - a) * tx;
        const v4f bot = c + (d - c) * tx;
        dst[px * (IMG_C / 4)] = top + (bot - top) * ty;   // plain store
    }
}

extern "C" void kernel_launch(void* const* d_in, const int* in_sizes, int n_in,
                              void* d_out, int out_size, void* d_ws, size_t ws_size,
                              hipStream_t stream) {
    const float* img  = (const float*)d_in[0];
    const int*   rois = (const int*)d_in[1];
    float*       out  = (float*)d_out;
    const int R = in_sizes[1] / 4;                  // rois: (1, R, 4)
    const int n_rows = R * POOLSZ;                  // 1024*7 = 7168 blocks
    const int rowsPerXcd = (n_rows % NUM_XCD == 0) ? (n_rows / NUM_XCD) : 0;

    int* order = nullptr;
    if (ws_size >= (size_t)n_rows * sizeof(int)) {
        order = (int*)d_ws;
        row_sort_kernel<<<1, 256, 0, stream>>>(rois, order, R);
    }
    roi_pool_row_kernel<<<n_rows, 256, 0, stream>>>(img, rois, out, rowsPerXcd, order);
}

// Round 4
// 236.076 us; speedup vs baseline: 1.1034x; 1.1034x over previous
//
#include <hip/hip_runtime.h>

// ROI bilinear pooling (tf.image.resize half-pixel centers), POOL=7.
// img: (1, 64, 64, 1024) fp32, NHWC. rois: (1, R, 4) int32 = [x, y, w, h].
// out: (1, R, 7, 7, 1024) fp32.
//
// R8 = LDS inversion. R7 post-mortem: all scheduling/ordering/occupancy
// variants are neutral-or-worse; the invariant is ~822 MB of tap reads
// served by L3 (write stream thrashes L2), and 822+205 MB through L3 at
// ~9 TB/s ~= the pool kernel's ~107us. So: cut the volume, not the order.
// Bin the 7168 (roi,py) rows by source row y0 (y1 is always y0 or y0+1).
// One block per (bin, 128-ch split) stages the two image rows in LDS
// (64 KB) ONCE and serves every consumer from LDS. Global reads drop
// 822 MB -> 32 MB regardless of cache behavior. Writes unchanged.
// LDS reads: 32 lanes x 16 B contiguous = 512 B segments, conflict-free.

#define POOLSZ 7
#define IMG_H 64
#define IMG_W 64
#define IMG_C 1024
#define NUM_XCD 8
#define SPLITS 8                  // channel splits: 128 ch per block
#define CH_V4 (IMG_C / 4)         // 256 v4f per pixel
#define SPLIT_V4 (CH_V4 / SPLITS) // 32 v4f per split

typedef float v4f __attribute__((ext_vector_type(4)));

__device__ __forceinline__ int src_y0(int ry, int rh, int py) {
    const float scy  = (float)rh * (1.0f / (float)POOLSZ);
    const float srcy = ((float)py + 0.5f) * scy - 0.5f;
    const int   iy   = (int)floorf(srcy);
    return ry + min(max(iy, 0), rh - 1);
}

// Counting-sort the R*7 (roi,py) rows by source row y0 (64 bins).
// Emits order[] (permutation of 0..R*7-1) and binStart[65].
__global__ __launch_bounds__(256) void row_sort_kernel(
    const int* __restrict__ rois, int* __restrict__ order,
    int* __restrict__ binStart, int R) {
    __shared__ int cnt[64];
    __shared__ int ofs[64];
    const int t = threadIdx.x;
    const int n = R * POOLSZ;
    if (t < 64) cnt[t] = 0;
    __syncthreads();
    for (int i = t; i < n; i += 256) {
        const int r  = i / POOLSZ;
        const int py = i - r * POOLSZ;
        const int y0 = src_y0(rois[r * 4 + 1], rois[r * 4 + 3], py) & 63;
        atomicAdd(&cnt[y0], 1);
    }
    __syncthreads();
    if (t == 0) {
        int s = 0;
        for (int i = 0; i < 64; ++i) { ofs[i] = s; binStart[i] = s; s += cnt[i]; }
        binStart[64] = s;
    }
    __syncthreads();
    for (int i = t; i < n; i += 256) {
        const int r  = i / POOLSZ;
        const int py = i - r * POOLSZ;
        const int y0 = src_y0(rois[r * 4 + 1], rois[r * 4 + 3], py) & 63;
        const int p  = atomicAdd(&ofs[y0], 1);
        order[p] = i;
    }
}

// One block per (y0-bin, channel split). Stage rows {bin, bin+1} x 128 ch
// in LDS, then each 32-lane group streams the bin's (roi,py) rows:
// 7 cells, 4 LDS taps each, blend, 512 B store per cell.
__global__ __launch_bounds__(256, 2) void roi_pool_bin_kernel(
    const float* __restrict__ img,
    const int* __restrict__ rois,
    float* __restrict__ out,
    const int* __restrict__ order,
    const int* __restrict__ binStart) {
    const int bin   = blockIdx.x >> 3;           // 0..63 = source row y0
    const int split = blockIdx.x & (SPLITS - 1); // 0..7  = 128-ch slice
    const int start = binStart[bin];
    const int cnt   = binStart[bin + 1] - start;
    if (cnt == 0) return;

    __shared__ v4f lds[2 * IMG_W * SPLIT_V4];    // 2 rows x 64 px x 32 v4f = 64 KB
    const int t = threadIdx.x;
    {   // stage: 4096 v4f, 16 per thread, coalesced 512 B runs
        const v4f* __restrict__ img4 = (const v4f*)img;
        const int y_hi = min(bin + 1, IMG_H - 1);
#pragma unroll
        for (int k = 0; k < 16; ++k) {
            const int j   = t + k * 256;         // 0..4095
            const int row = j >> 11;             // 0 | 1
            const int rem = j & 2047;
            const int x   = rem >> 5;            // 0..63
            const int c4  = rem & 31;            // 0..31
            const int y   = row ? y_hi : bin;
            lds[j] = img4[((size_t)(y * IMG_W + x)) * CH_V4 + split * SPLIT_V4 + c4];
        }
    }
    __syncthreads();

    const int grp  = t >> 5;   // 0..7: concurrent row streams
    const int lane = t & 31;   // v4f channel within split
    v4f* __restrict__ out4 = (v4f*)out;

    for (int row = grp; row < cnt; row += 8) {
        const int rid = order[start + row];      // = r*7 + py
        const int r   = rid / POOLSZ;
        const int py  = rid - r * POOLSZ;
        const int4 roi = ((const int4*)rois)[r];
        const int rx = roi.x, ry = roi.y, rw = roi.z, rh = roi.w;

        const float scy  = (float)rh * (1.0f / (float)POOLSZ);
        const float srcy = ((float)py + 0.5f) * scy - 0.5f;
        const float fy   = floorf(srcy);
        const float ty   = srcy - fy;
        const int   iy   = (int)fy;
        // y0 == bin by construction; y1 in {bin, bin+1}
        const int y1 = ry + min(max(iy + 1, 0), rh - 1);
        const int l1 = (y1 - bin) << 11;         // 0 or 2048 (v4f units)

        const float scx = (float)rw * (1.0f / (float)POOLSZ);
        const size_t obase = (size_t)rid * (POOLSZ * CH_V4) + split * SPLIT_V4 + lane;
#pragma unroll
        for (int px = 0; px < POOLSZ; ++px) {
            const float srcx = ((float)px + 0.5f) * scx - 0.5f;
            const float fx   = floorf(srcx);
            const float tx   = srcx - fx;
            const int   ix   = (int)fx;
            const int xo0 = (rx + min(max(ix,     0), rw - 1)) << 5;  // *32 v4f
            const int xo1 = (rx + min(max(ix + 1, 0), rw - 1)) << 5;

            const v4f a = lds[xo0 + lane];
            const v4f b = lds[xo1 + lane];
            const v4f c = lds[l1 + xo0 + lane];
            const v4f d = lds[l1 + xo1 + lane];

            const v4f top = a + (b - a) * tx;
            const v4f bot = c + (d - c) * tx;
            out4[obase + (size_t)px * CH_V4] = top + (bot - top) * ty;
        }
    }
}

// Fallback (no workspace): R6 streaming row kernel, identity order.
__global__ __launch_bounds__(256, 4) void roi_pool_row_kernel(
    const float* __restrict__ img,
    const int* __restrict__ rois,
    float* __restrict__ out) {
    const int rowIdx = blockIdx.x;
    const int r  = rowIdx / POOLSZ;
    const int py = rowIdx - r * POOLSZ;

    const int4 roi = ((const int4*)rois)[r];
    const int rx = roi.x, ry = roi.y, rw = roi.z, rh = roi.w;

    const float scy  = (float)rh * (1.0f / (float)POOLSZ);
    const float srcy = ((float)py + 0.5f) * scy - 0.5f;
    const float fy   = floorf(srcy);
    const float ty   = srcy - fy;
    const int   iy   = (int)fy;
    const int   y0   = ry + min(max(iy,     0), rh - 1);
    const int   y1   = ry + min(max(iy + 1, 0), rh - 1);

    const int c4 = threadIdx.x;
    const v4f* __restrict__ base = (const v4f*)img + c4;
    const int rb0 = y0 * (IMG_W * CH_V4);
    const int rb1 = y1 * (IMG_W * CH_V4);
    v4f* __restrict__ dst =
        (v4f*)out + ((size_t)r * POOLSZ + py) * POOLSZ * CH_V4 + c4;

    const float scx = (float)rw * (1.0f / (float)POOLSZ);
#pragma unroll
    for (int px = 0; px < POOLSZ; ++px) {
        const float srcx = ((float)px + 0.5f) * scx - 0.5f;
        const float fx   = floorf(srcx);
        const float tx   = srcx - fx;
        const int   ix   = (int)fx;
        const int   xo0  = (rx + min(max(ix,     0), rw - 1)) * CH_V4;
        const int   xo1  = (rx + min(max(ix + 1, 0), rw - 1)) * CH_V4;

        const v4f a = base[rb0 + xo0];
        const v4f b = base[rb0 + xo1];
        const v4f c = base[rb1 + xo0];
        const v4f d = base[rb1 + xo1];

        const v4f top = a + (b - a) * tx;
        const v4f bot = c + (d - c) * tx;
        dst[px * CH_V4] = top + (bot - top) * ty;
    }
}

extern "C" void kernel_launch(void* const* d_in, const int* in_sizes, int n_in,
                              void* d_out, int out_size, void* d_ws, size_t ws_size,
                              hipStream_t stream) {
    const float* img  = (const float*)d_in[0];
    const int*   rois = (const int*)d_in[1];
    float*       out  = (float*)d_out;
    const int R = in_sizes[1] / 4;                  // rois: (1, R, 4)
    const int n_rows = R * POOLSZ;

    const size_t ws_need = (size_t)(n_rows + 65) * sizeof(int);
    if (ws_size >= ws_need) {
        int* order    = (int*)d_ws;
        int* binStart = order + n_rows;
        row_sort_kernel<<<1, 256, 0, stream>>>(rois, order, binStart, R);
        roi_pool_bin_kernel<<<64 * SPLITS, 256, 0, stream>>>(
            img, rois, out, order, binStart);
    } else {
        roi_pool_row_kernel<<<n_rows, 256, 0, stream>>>(img, rois, out);
    }
}